// Round 8
// baseline (25.518 us; speedup 1.0000x reference)
//
#include <hip/hip_runtime.h>
#include <hip/hip_bf16.h>
#include <math.h>

#define B_ 128
#define S_ 512
#define E_ 64
#define PAD_ 72  // bf16/row; 36-dword stride spreads b128 reads evenly (8/bank)

typedef short bf16x8 __attribute__((ext_vector_type(8)));
typedef float f32x4 __attribute__((ext_vector_type(4)));

__device__ __forceinline__ unsigned short f2b(float f) {
  __hip_bfloat16 h = __float2bfloat16(f);
  unsigned short u;
  __builtin_memcpy(&u, &h, 2);
  return u;
}

// 512 blocks x 512 thr (8 waves), 2 blocks/CU (launch_bounds(512,4) caps VGPR
// at 128). Block = (batch b, s-quarter sq): owns 128 s-rows, scans all 512 n.
// Each block normalizes the full V panel into its own LDS (VALU dup ~0.2us
// chip-wide, HBM dedup via same-XCD quartet swizzle). U rows live in registers
// as MFMA A-fragments. Wave (ws,wn) = 64 s x 128 n; mask as MFMA C-init.
__global__ __launch_bounds__(512, 4) void fused_kernel(
    const float* __restrict__ ue, const float* __restrict__ ve,
    const float* __restrict__ cw, const float* __restrict__ mask,
    const float* __restrict__ pw, const float* __restrict__ pb,
    float* __restrict__ out) {
  __shared__ unsigned short vlds[S_ * PAD_];  // 73728 B
  __shared__ float comb[4][128];              // 2048 B

  // bx -> (b, sq): xcd = bx&7 = b>>4; the 4 sq-siblings of a batch share an
  // XCD and dispatch at spacing 8 (near-simultaneous -> L2-share V panel).
  const int bx = blockIdx.x;
  const int b = (bx & 7) * 16 + (bx >> 5);
  const int sq = (bx >> 3) & 3;

  const int tid = threadIdx.x;
  const int w = tid >> 6;  // 8 waves
  const int lane = tid & 63;
  const int c = lane & 15;  // MFMA col class / row-within-16
  const int g = lane >> 4;  // k-group / 16-elem chunk
  const int ws = w >> 2;    // 0..1 : 64 s-rows
  const int wn = w & 3;     // 0..3 : 128 n

  const float w0 = pw[0];
  const float* __restrict__ vb = ve + (size_t)b * S_ * E_;
  const float* __restrict__ cwb = cw + (size_t)b * S_;
  const float* __restrict__ ub = ue + ((size_t)b * S_ + sq * 128) * E_;
  const float* __restrict__ mb = mask + (size_t)b * S_;

  // ---- Stage all V loads up-front (16 f32x4; drains as processed).
  //      Wave w owns V rows [w*64, +64); pass p: row w*64+p*16+c, elems [16g,+16)
  f32x4 xv[4][4];
  float cwv[4];
#pragma unroll
  for (int p = 0; p < 4; ++p) {
    const int row = w * 64 + p * 16 + c;
    const float* src = vb + (size_t)row * E_ + g * 16;
#pragma unroll
    for (int i = 0; i < 4; ++i) xv[p][i] = ((const f32x4*)src)[i];
    cwv[p] = cwb[row];
  }
  float pen[8];  // mask penalty for this wave's 8 n-tiles, column c
#pragma unroll
  for (int j = 0; j < 8; ++j)
    pen[j] = (mb[(wn * 8 + j) * 16 + c] > 0.5f) ? 0.0f : -1e30f;

  // ---- Normalize V -> LDS bf16 ----
#pragma unroll
  for (int p = 0; p < 4; ++p) {
    float ss = 0.f;
#pragma unroll
    for (int i = 0; i < 4; ++i)
#pragma unroll
      for (int j = 0; j < 4; ++j) ss = fmaf(xv[p][i][j], xv[p][i][j], ss);
    ss += __shfl_xor(ss, 16);  // reduce over the 4 g-lanes sharing the row
    ss += __shfl_xor(ss, 32);
    float s = (w0 * cwv[p]) / fmaxf(sqrtf(ss), 1e-7f);
    bf16x8 o0, o1;
#pragma unroll
    for (int j = 0; j < 4; ++j) {
      o0[j] = (short)f2b(xv[p][0][j] * s); o0[4 + j] = (short)f2b(xv[p][1][j] * s);
      o1[j] = (short)f2b(xv[p][2][j] * s); o1[4 + j] = (short)f2b(xv[p][3][j] * s);
    }
    unsigned short* dst = vlds + (size_t)(w * 64 + p * 16 + c) * PAD_ + g * 16;
    *(bf16x8*)dst = o0;
    *(bf16x8*)(dst + 8) = o1;
  }

  // ---- U: 4 s-tiles (rows ws*64 + st*16 + c) -> register A-fragments.
  //      Lane(c,g) loads k-chunks [8g,+8) and [32+8g,+8); union over g covers
  //      the row, so sum-sq reduces with the same 2 shuffles. Tile-sequential
  //      to cap live registers at 16.
  bf16x8 a[4][2];
#pragma unroll
  for (int st = 0; st < 4; ++st) {
    const float* r_ = ub + (size_t)(ws * 64 + st * 16 + c) * E_;
    f32x4 u0 = *(const f32x4*)(r_ + 8 * g);
    f32x4 u1 = *(const f32x4*)(r_ + 8 * g + 4);
    f32x4 u2 = *(const f32x4*)(r_ + 32 + 8 * g);
    f32x4 u3 = *(const f32x4*)(r_ + 32 + 8 * g + 4);
    float ss = 0.f;
#pragma unroll
    for (int j = 0; j < 4; ++j)
      ss = fmaf(u0[j], u0[j],
           fmaf(u1[j], u1[j], fmaf(u2[j], u2[j], fmaf(u3[j], u3[j], ss))));
    ss += __shfl_xor(ss, 16);
    ss += __shfl_xor(ss, 32);
    float s = 1.0f / fmaxf(sqrtf(ss), 1e-7f);
#pragma unroll
    for (int j = 0; j < 4; ++j) {
      a[st][0][j] = (short)f2b(u0[j] * s);
      a[st][0][4 + j] = (short)f2b(u1[j] * s);
      a[st][1][j] = (short)f2b(u2[j] * s);
      a[st][1][4 + j] = (short)f2b(u3[j] * s);
    }
  }

  __syncthreads();  // V panel ready

  // ---- Phase 2: scan this wave's 8 n-tiles; mask folded into C-operand ----
  float r[4][4];
#pragma unroll
  for (int st = 0; st < 4; ++st)
#pragma unroll
    for (int i = 0; i < 4; ++i) r[st][i] = -INFINITY;

#pragma unroll
  for (int j = 0; j < 8; ++j) {
    const int it = wn * 8 + j;
    const unsigned short* vr = vlds + (size_t)(it * 16 + c) * PAD_ + g * 8;
    bf16x8 b0 = *(const bf16x8*)(vr);
    bf16x8 b1 = *(const bf16x8*)(vr + 32);
    f32x4 ci = {pen[j], pen[j], pen[j], pen[j]};
#pragma unroll
    for (int st = 0; st < 4; ++st) {
      f32x4 acc = __builtin_amdgcn_mfma_f32_16x16x32_bf16(a[st][0], b0, ci, 0, 0, 0);
      acc = __builtin_amdgcn_mfma_f32_16x16x32_bf16(a[st][1], b1, acc, 0, 0, 0);
      r[st][0] = fmaxf(r[st][0], acc[0]);
      r[st][1] = fmaxf(r[st][1], acc[1]);
      r[st][2] = fmaxf(r[st][2], acc[2]);
      r[st][3] = fmaxf(r[st][3], acc[3]);
    }
  }

  // ---- Reduce over 16 column-lanes (xor 1,2,4,8 stays in kg group) ----
#pragma unroll
  for (int st = 0; st < 4; ++st)
#pragma unroll
    for (int i = 0; i < 4; ++i) {
      float v = r[st][i];
      v = fmaxf(v, __shfl_xor(v, 1)); v = fmaxf(v, __shfl_xor(v, 2));
      v = fmaxf(v, __shfl_xor(v, 4)); v = fmaxf(v, __shfl_xor(v, 8));
      r[st][i] = v;
    }

  if (c == 0) {
#pragma unroll
    for (int st = 0; st < 4; ++st)
#pragma unroll
      for (int i = 0; i < 4; ++i)
        comb[wn][ws * 64 + st * 16 + g * 4 + i] = r[st][i];
  }

  __syncthreads();

  // ---- Combine the 4 n-splits + sigmoid, 128 outputs ----
  if (tid < 128) {
    float v = fmaxf(fmaxf(comb[0][tid], comb[1][tid]),
                    fmaxf(comb[2][tid], comb[3][tid]));
    float bias = pb[0];
    out[(size_t)b * S_ + sq * 128 + tid] =
        (v < -1e29f) ? 0.0f : 1.0f / (1.0f + expf(-(v + bias)));
  }
}

extern "C" void kernel_launch(void* const* d_in, const int* in_sizes, int n_in,
                              void* d_out, int out_size, void* d_ws, size_t ws_size,
                              hipStream_t stream) {
  const float* ue = (const float*)d_in[0];
  const float* ve = (const float*)d_in[1];
  const float* cw = (const float*)d_in[2];
  const float* mask = (const float*)d_in[3];
  const float* pw = (const float*)d_in[4];
  const float* pb = (const float*)d_in[5];
  float* out = (float*)d_out;

  hipLaunchKernelGGL(fused_kernel, dim3(4 * B_), dim3(512), 0, stream,
                     ue, ve, cw, mask, pw, pb, out);
}

// Round 9
// 17.563 us; speedup vs baseline: 1.4529x; 1.4529x over previous
//
#include <hip/hip_runtime.h>
#include <hip/hip_bf16.h>
#include <math.h>

#define B_ 128
#define S_ 512
#define E_ 64
#define PAD_ 72  // bf16/row in LDS; 36-dword row stride keeps DS ops bank-clean

typedef short bf16x8 __attribute__((ext_vector_type(8)));
typedef float f32x4 __attribute__((ext_vector_type(4)));

__device__ __forceinline__ unsigned short f2b(float f) {
  __hip_bfloat16 h = __float2bfloat16(f);
  unsigned short u;
  __builtin_memcpy(&u, &h, 2);
  return u;
}

// Coalesced 16-row normalize: wave reads rows [rbase, rbase+16) of a [*, 64]
// f32 matrix with 4 fully-contiguous 1KB instructions (lane*16B). Lane holds
// cols [4c,4c+4) of rows i*4+g. Sum-sq reduces over the 16 c-lanes. Scale_i
// supplied per row-quad. Emits bf16 to lds rows [rbase_lds, +16), col 4c.
__device__ __forceinline__ void norm16_coalesced(
    const float* __restrict__ src,  // row rbase, elem 0
    const float* __restrict__ scl,  // per-row numerator: scl[row] or nullptr
    float w0, int c, int g, int lane,
    unsigned short* __restrict__ lds_base) {  // row rbase_lds, elem 0
  f32x4 x[4];
  float sn[4];
#pragma unroll
  for (int i = 0; i < 4; ++i) x[i] = *(const f32x4*)(src + i * 256 + lane * 4);
#pragma unroll
  for (int i = 0; i < 4; ++i)
    sn[i] = scl ? scl[i * 4 + g] * w0 : 1.0f;
#pragma unroll
  for (int i = 0; i < 4; ++i) {
    float ss = x[i][0] * x[i][0] + x[i][1] * x[i][1] +
               x[i][2] * x[i][2] + x[i][3] * x[i][3];
    ss += __shfl_xor(ss, 1); ss += __shfl_xor(ss, 2);
    ss += __shfl_xor(ss, 4); ss += __shfl_xor(ss, 8);
    float s = sn[i] / fmaxf(sqrtf(ss), 1e-7f);
    ushort4 o;
    o.x = f2b(x[i][0] * s); o.y = f2b(x[i][1] * s);
    o.z = f2b(x[i][2] * s); o.w = f2b(x[i][3] * s);
    *(ushort4*)(lds_base + (size_t)(i * 4 + g) * PAD_ + c * 4) = o;
  }
}

// Fused, 256 blocks x 1024 thr (16 waves), 1 block/CU. Block = (batch, shalf).
// Staggered-half V (own half from HBM, other half after barrier#1 -> sibling's
// L2 lines), phase-2a overlaps other-half loads. Coalesced phase-1 loads.
__global__ __launch_bounds__(1024) void fused_kernel(
    const float* __restrict__ ue, const float* __restrict__ ve,
    const float* __restrict__ cw, const float* __restrict__ mask,
    const float* __restrict__ pw, const float* __restrict__ pb,
    float* __restrict__ out) {
  __shared__ unsigned short vlds[S_ * PAD_];   // 73728 B
  __shared__ unsigned short ulds[256 * PAD_];  // 36864 B
  __shared__ float comb[4][256];               // 4096 B

  // bijective swizzle: sibling blocks (same b, shalf 0/1) share an XCD (bx%8)
  const int bx = blockIdx.x;
  const int b = (bx & 7) * 16 + (bx >> 4);
  const int shalf = (bx >> 3) & 1;

  const int tid = threadIdx.x;
  const int wv = tid >> 6;  // 16 waves
  const int lane = tid & 63;
  const int c = lane & 15;
  const int g = lane >> 4;
  const int ws = wv >> 2;  // s-split (0..3): 64 s-rows
  const int wn = wv & 3;   // n-split (0..3): 4 n-tiles per half

  const float w0 = pw[0];
  const float* __restrict__ vb = ve + (size_t)b * S_ * E_;
  const float* __restrict__ cwb = cw + (size_t)b * S_;
  const float* __restrict__ ub = ue + ((size_t)b * S_ + shalf * 256) * E_;
  const float* __restrict__ mb = mask + (size_t)b * S_;

  const int vown = shalf * 256 + wv * 16;      // own-half V row base (16 rows)
  const int voth = (1 - shalf) * 256 + wv * 16;  // other-half base
  const int urow = wv * 16;                    // U row base

  float pen[8];  // own tiles then other tiles, this wave's columns
#pragma unroll
  for (int j = 0; j < 4; ++j) {
    pen[j] = (mb[(shalf * 16 + wn * 4 + j) * 16 + c] > 0.5f) ? 0.0f : -1e30f;
    pen[4 + j] =
        (mb[((1 - shalf) * 16 + wn * 4 + j) * 16 + c] > 0.5f) ? 0.0f : -1e30f;
  }

  // ---- Phase 1: own-half V + U, coalesced ----
  norm16_coalesced(vb + (size_t)vown * E_, cwb + vown, w0, c, g, lane,
                   vlds + (size_t)vown * PAD_);
  norm16_coalesced(ub + (size_t)urow * E_, nullptr, 1.0f, c, g, lane,
                   ulds + (size_t)urow * PAD_);

  __syncthreads();  // barrier #1: own V-half + U ready

  // ---- Other-half V: issue loads now (fly under phase-2a) ----
  const float* psrc = vb + (size_t)voth * E_;
  f32x4 y[4];
#pragma unroll
  for (int i = 0; i < 4; ++i) y[i] = *(const f32x4*)(psrc + i * 256 + lane * 4);
  float cwo[4];
#pragma unroll
  for (int i = 0; i < 4; ++i) cwo[i] = cwb[voth + i * 4 + g];

  // ---- A-fragments from ulds ----
  const unsigned short* urp = ulds + (size_t)(ws * 64 + c) * PAD_ + g * 8;
  bf16x8 a[4][2];
#pragma unroll
  for (int st = 0; st < 4; ++st) {
    a[st][0] = *(const bf16x8*)(urp + st * 16 * PAD_);
    a[st][1] = *(const bf16x8*)(urp + st * 16 * PAD_ + 32);
  }

  float r[4][4];
#pragma unroll
  for (int st = 0; st < 4; ++st)
#pragma unroll
    for (int i = 0; i < 4; ++i) r[st][i] = -INFINITY;

  // ---- Phase-2a: scan OWN half ----
#pragma unroll
  for (int j = 0; j < 4; ++j) {
    const int it = shalf * 16 + wn * 4 + j;
    const unsigned short* vr = vlds + (size_t)(it * 16 + c) * PAD_ + g * 8;
    bf16x8 b0 = *(const bf16x8*)(vr);
    bf16x8 b1 = *(const bf16x8*)(vr + 32);
    f32x4 ci = {pen[j], pen[j], pen[j], pen[j]};
#pragma unroll
    for (int st = 0; st < 4; ++st) {
      f32x4 acc = __builtin_amdgcn_mfma_f32_16x16x32_bf16(a[st][0], b0, ci, 0, 0, 0);
      acc = __builtin_amdgcn_mfma_f32_16x16x32_bf16(a[st][1], b1, acc, 0, 0, 0);
      r[st][0] = fmaxf(r[st][0], acc[0]);
      r[st][1] = fmaxf(r[st][1], acc[1]);
      r[st][2] = fmaxf(r[st][2], acc[2]);
      r[st][3] = fmaxf(r[st][3], acc[3]);
    }
  }

  // ---- Normalize other-half V -> LDS (loads already in flight) ----
#pragma unroll
  for (int i = 0; i < 4; ++i) {
    float ss = y[i][0] * y[i][0] + y[i][1] * y[i][1] +
               y[i][2] * y[i][2] + y[i][3] * y[i][3];
    ss += __shfl_xor(ss, 1); ss += __shfl_xor(ss, 2);
    ss += __shfl_xor(ss, 4); ss += __shfl_xor(ss, 8);
    float s = (w0 * cwo[i]) / fmaxf(sqrtf(ss), 1e-7f);
    ushort4 o;
    o.x = f2b(y[i][0] * s); o.y = f2b(y[i][1] * s);
    o.z = f2b(y[i][2] * s); o.w = f2b(y[i][3] * s);
    *(ushort4*)(vlds + (size_t)(voth + i * 4 + g) * PAD_ + c * 4) = o;
  }

  __syncthreads();  // barrier #2: other V-half ready

  // ---- Phase-2b: scan OTHER half ----
#pragma unroll
  for (int j = 0; j < 4; ++j) {
    const int it = (1 - shalf) * 16 + wn * 4 + j;
    const unsigned short* vr = vlds + (size_t)(it * 16 + c) * PAD_ + g * 8;
    bf16x8 b0 = *(const bf16x8*)(vr);
    bf16x8 b1 = *(const bf16x8*)(vr + 32);
    f32x4 ci = {pen[4 + j], pen[4 + j], pen[4 + j], pen[4 + j]};
#pragma unroll
    for (int st = 0; st < 4; ++st) {
      f32x4 acc = __builtin_amdgcn_mfma_f32_16x16x32_bf16(a[st][0], b0, ci, 0, 0, 0);
      acc = __builtin_amdgcn_mfma_f32_16x16x32_bf16(a[st][1], b1, acc, 0, 0, 0);
      r[st][0] = fmaxf(r[st][0], acc[0]);
      r[st][1] = fmaxf(r[st][1], acc[1]);
      r[st][2] = fmaxf(r[st][2], acc[2]);
      r[st][3] = fmaxf(r[st][3], acc[3]);
    }
  }

  // ---- Reduce over 16 column-lanes ----
#pragma unroll
  for (int st = 0; st < 4; ++st)
#pragma unroll
    for (int i = 0; i < 4; ++i) {
      float v = r[st][i];
      v = fmaxf(v, __shfl_xor(v, 1)); v = fmaxf(v, __shfl_xor(v, 2));
      v = fmaxf(v, __shfl_xor(v, 4)); v = fmaxf(v, __shfl_xor(v, 8));
      r[st][i] = v;
    }

  if (c == 0) {
#pragma unroll
    for (int st = 0; st < 4; ++st)
#pragma unroll
      for (int i = 0; i < 4; ++i)
        comb[wn][ws * 64 + st * 16 + g * 4 + i] = r[st][i];
  }

  __syncthreads();  // barrier #3

  if (tid < 256) {
    float v = fmaxf(fmaxf(comb[0][tid], comb[1][tid]),
                    fmaxf(comb[2][tid], comb[3][tid]));
    float bias = pb[0];
    out[(size_t)b * S_ + shalf * 256 + tid] =
        (v < -1e29f) ? 0.0f : 1.0f / (1.0f + expf(-(v + bias)));
  }
}

extern "C" void kernel_launch(void* const* d_in, const int* in_sizes, int n_in,
                              void* d_out, int out_size, void* d_ws, size_t ws_size,
                              hipStream_t stream) {
  const float* ue = (const float*)d_in[0];
  const float* ve = (const float*)d_in[1];
  const float* cw = (const float*)d_in[2];
  const float* mask = (const float*)d_in[3];
  const float* pw = (const float*)d_in[4];
  const float* pb = (const float*)d_in[5];
  float* out = (float*)d_out;

  hipLaunchKernelGGL(fused_kernel, dim3(2 * B_), dim3(1024), 0, stream,
                     ue, ve, cw, mask, pw, pb, out);
}